// Round 1
// baseline (36.075 us; speedup 1.0000x reference)
//
#include <hip/hip_runtime.h>

// YOLO loss: B=32, A=5, C=80, gh=gw=52, HW=2704.
// Inputs (setup_inputs order):
//   d_in[0] net_out    (B, gh, gw, A*(5+C)) f32  == flat (B, A, 85, HW)
//   d_in[1] targets    (B, A, 6, HW)        f32  (already multiplied by anchor_mask)
//   d_in[2] anchor_mask(B, A, 1, HW)        f32  {0,1}
//   d_in[3] obj_mask   (B, A, HW)           f32  {0,1}
//   d_in[4] anchors    (5, 2)               f32
// Output: scalar f32 total loss.

constexpr int B_  = 32;
constexpr int A_  = 5;
constexpr int C_  = 80;
constexpr int GW_ = 52;
constexpr int GH_ = 52;
constexpr int HW_ = GW_ * GH_;
constexpr int NCH = 5 + C_;          // 85
constexpr int TOTAL = B_ * A_ * HW_; // 432640

constexpr float NET_W = 416.0f;
constexpr float NET_H = 416.0f;
constexpr float OBJ_THRESH  = 0.5f;
constexpr float COORD_SCALE = 5.0f;
constexpr float NOOBJ_SCALE = 1.0f;
constexpr float OBJ_SCALE   = 5.0f;
constexpr float CLASS_SCALE = 1.0f;

__device__ __forceinline__ float sigmoidf_(float x) {
    return 1.0f / (1.0f + __expf(-x));
}

__global__ __launch_bounds__(256) void yolo_loss_kernel(
    const float* __restrict__ net,     // (B*A*85*HW)
    const float* __restrict__ tgt,     // (B*A*6*HW)
    const float* __restrict__ amask,   // (B*A*HW)
    const float* __restrict__ omask,   // (B*A*HW)
    const float* __restrict__ anchors, // (5*2)
    float* __restrict__ out)
{
    const int i = blockIdx.x * blockDim.x + threadIdx.x;
    float loss = 0.0f;

    if (i < TOTAL) {
        const int hw = i % HW_;
        const int ba = i / HW_;      // b*A + a
        const int a  = ba % A_;

        const size_t nbase = (size_t)ba * NCH * HW_ + hw; // channel c at nbase + c*HW_
        const size_t tbase = (size_t)ba * 6   * HW_ + hw;

        const float cm = amask[i];   // conf_mask / anchor_mask, {0,1}
        const float om = omask[i];   // obj_mask, {0,1}

        // ---- dense phase: conf / noobj term (needed at every cell) ----
        const float conf_raw = net[nbase + 4 * (size_t)HW_];
        const float conf     = sigmoidf_(conf_raw);
        const float t_conf   = tgt[tbase + 4 * (size_t)HW_];
        const float d        = conf - t_conf;
        const float diff2    = d * d;

        loss += diff2 * (1.0f - om) * NOOBJ_SCALE;  // noobj1

        const bool need_box = (cm != 0.0f) || (om != 0.0f);
        if (need_box) {
            const float aw = anchors[2 * a];
            const float ah = anchors[2 * a + 1];

            const float p0 = net[nbase + 0 * (size_t)HW_];
            const float p1 = net[nbase + 1 * (size_t)HW_];
            const float p2 = net[nbase + 2 * (size_t)HW_];
            const float p3 = net[nbase + 3 * (size_t)HW_];
            const float t0 = tgt[tbase + 0 * (size_t)HW_];
            const float t1 = tgt[tbase + 1 * (size_t)HW_];
            const float t2 = tgt[tbase + 2 * (size_t)HW_];
            const float t3 = tgt[tbase + 3 * (size_t)HW_];

            const float sx = sigmoidf_(p0);
            const float sy = sigmoidf_(p1);

            if (cm != 0.0f) {
                // xy loss
                const float dx = sx - t0;
                const float dy = sy - t1;
                float xy_l = dx * dx + dy * dy;

                // wh loss (scale space)
                const float pws = __expf(p2) * aw / NET_W;
                const float phs = __expf(p3) * ah / NET_H;
                const float tws = __expf(t2) * aw / NET_W;
                const float ths = __expf(t3) * ah / NET_H;
                const float dw = pws - tws;
                const float dh = phs - ths;
                float wh_l = dw * dw + dh * dh;

                loss += (xy_l + wh_l) * cm * COORD_SCALE;
                loss += diff2 * cm * OBJ_SCALE;

                // class CE via online log-softmax over 80 logits
                const int tc = (int)tgt[tbase + 5 * (size_t)HW_];
                float m = -1e30f, s = 0.0f, logit_tc = 0.0f;
                #pragma unroll 4
                for (int c = 0; c < C_; ++c) {
                    const float x = net[nbase + (size_t)(5 + c) * HW_];
                    if (c == tc) logit_tc = x;
                    const float mn = fmaxf(m, x);
                    s = s * __expf(m - mn) + __expf(x - mn);
                    m = mn;
                }
                const float ce = -(logit_tc - m - __logf(s));
                loss += ce * cm * CLASS_SCALE;
            }

            const float no_resp = (1.0f - cm) * om;
            if (no_resp != 0.0f) {
                const float col = (float)(hw % GW_);
                const float row = (float)(hw / GW_);

                // pred box
                const float pcx = (sx + col) / (float)GW_ * NET_W;
                const float pcy = (sy + row) / (float)GH_ * NET_H;
                const float pw  = __expf(p2) * aw;
                const float ph  = __expf(p3) * ah;
                const float px1 = pcx - 0.5f * pw;
                const float py1 = pcy - 0.5f * ph;
                const float px2 = px1 + pw;
                const float py2 = py1 + ph;

                // gt box
                const float gcx = (t0 + col) / (float)GW_ * NET_W;
                const float gcy = (t1 + row) / (float)GH_ * NET_H;
                const float gwd = __expf(t2) * aw;
                const float ghd = __expf(t3) * ah;
                const float gx1 = gcx - 0.5f * gwd;
                const float gy1 = gcy - 0.5f * ghd;
                const float gx2 = gx1 + gwd;
                const float gy2 = gy1 + ghd;

                const float iw = fmaxf(fminf(px2, gx2) - fmaxf(px1, gx1), 0.0f);
                const float ih = fmaxf(fminf(py2, gy2) - fmaxf(py1, gy1), 0.0f);
                const float inter  = iw * ih;
                const float area_p = (px2 - px1) * (py2 - py1);
                const float area_g = (gx2 - gx1) * (gy2 - gy1);
                const float iou = inter / (area_p + area_g - inter + 1e-9f);
                if (iou < OBJ_THRESH) {
                    loss += diff2 * no_resp * NOOBJ_SCALE;
                }
            }
        }
    }

    // ---- block reduction: wave shuffle -> LDS -> one atomic ----
    #pragma unroll
    for (int off = 32; off > 0; off >>= 1)
        loss += __shfl_down(loss, off, 64);

    __shared__ float wsum[4];
    const int lane = threadIdx.x & 63;
    const int wid  = threadIdx.x >> 6;
    if (lane == 0) wsum[wid] = loss;
    __syncthreads();
    if (threadIdx.x == 0) {
        atomicAdd(out, wsum[0] + wsum[1] + wsum[2] + wsum[3]);
    }
}

extern "C" void kernel_launch(void* const* d_in, const int* in_sizes, int n_in,
                              void* d_out, int out_size, void* d_ws, size_t ws_size,
                              hipStream_t stream) {
    const float* net     = (const float*)d_in[0];
    const float* tgt     = (const float*)d_in[1];
    const float* amask   = (const float*)d_in[2];
    const float* omask   = (const float*)d_in[3];
    const float* anchors = (const float*)d_in[4];
    float* out = (float*)d_out;

    // d_out is poisoned once before timing and never re-poisoned between
    // replays; we accumulate with atomics, so zero it every launch.
    hipMemsetAsync(out, 0, sizeof(float), stream);

    constexpr int BLOCK = 256;
    const int grid = (TOTAL + BLOCK - 1) / BLOCK;
    yolo_loss_kernel<<<grid, BLOCK, 0, stream>>>(net, tgt, amask, omask, anchors, out);
}

// Round 2
// 12.060 us; speedup vs baseline: 2.9914x; 2.9914x over previous
//
#include <hip/hip_runtime.h>

// YOLO loss: B=32, A=5, C=80, gh=gw=52, HW=2704.
// d_in[0] net_out (B,A,85,HW) f32 | d_in[1] targets (B,A,6,HW) f32 (pre-masked)
// d_in[2] anchor_mask (B,A,HW) {0,1} | d_in[3] obj_mask (B,A,HW) {0,1}
// d_in[4] anchors (5,2) f32.  Output: scalar f32.

constexpr int B_  = 32;
constexpr int A_  = 5;
constexpr int C_  = 80;
constexpr int GW_ = 52;
constexpr int GH_ = 52;
constexpr int HW_ = GW_ * GH_;
constexpr int NCH = 5 + C_;           // 85
constexpr int TOTAL = B_ * A_ * HW_;  // 432640 = 1690 * 256 exactly
constexpr int BLOCK = 256;
constexpr int GRID  = TOTAL / BLOCK;  // 1690

constexpr float NET_W = 416.0f;
constexpr float NET_H = 416.0f;
constexpr float OBJ_THRESH  = 0.5f;
constexpr float COORD_SCALE = 5.0f;
constexpr float NOOBJ_SCALE = 1.0f;
constexpr float OBJ_SCALE   = 5.0f;
constexpr float CLASS_SCALE = 1.0f;

__device__ __forceinline__ float sigmoidf_(float x) {
    return 1.0f / (1.0f + __expf(-x));
}

__global__ __launch_bounds__(256) void yolo_partial_kernel(
    const float* __restrict__ net,     // (B*A*85*HW)
    const float* __restrict__ tgt,     // (B*A*6*HW)
    const float* __restrict__ amask,   // (B*A*HW)
    const float* __restrict__ omask,   // (B*A*HW)
    const float* __restrict__ anchors, // (5*2)
    float* __restrict__ partial)       // (GRID)
{
    const int i    = blockIdx.x * blockDim.x + threadIdx.x;  // always < TOTAL
    const int lane = threadIdx.x & 63;

    const int hw = i % HW_;
    const int ba = i / HW_;      // b*A + a
    const int a  = ba % A_;

    // all offsets fit comfortably in 32 bits (net has 36.8M elements)
    const unsigned nbase = (unsigned)ba * (unsigned)(NCH * HW_) + (unsigned)hw;
    const unsigned tbase = (unsigned)ba * (unsigned)(6 * HW_)   + (unsigned)hw;

    const float cm = amask[i];   // {0,1}
    const float om = omask[i];   // {0,1}

    const bool want_ce  = (cm != 0.0f);
    const bool need_box = want_ce || (om != 0.0f);

    // ---- dense phase: conf term (every cell) ----
    const float conf = sigmoidf_(net[nbase + 4u * HW_]);
    // targets are pre-multiplied by anchor_mask -> t_conf == 0 where cm == 0
    float t_conf = 0.0f;
    if (want_ce) t_conf = tgt[tbase + 4u * HW_];
    const float d     = conf - t_conf;
    const float diff2 = d * d;

    float loss = diff2 * (1.0f - om) * NOOBJ_SCALE;   // noobj1

    int tc = 0;  // target class, valid only on want_ce lanes
    if (need_box) {
        const float aw = anchors[2 * a];
        const float ah = anchors[2 * a + 1];

        const float p0 = net[nbase + 0u * HW_];
        const float p1 = net[nbase + 1u * HW_];
        const float p2 = net[nbase + 2u * HW_];
        const float p3 = net[nbase + 3u * HW_];
        const float t0 = tgt[tbase + 0u * HW_];
        const float t1 = tgt[tbase + 1u * HW_];
        const float t2 = tgt[tbase + 2u * HW_];
        const float t3 = tgt[tbase + 3u * HW_];

        const float sx = sigmoidf_(p0);
        const float sy = sigmoidf_(p1);

        if (want_ce) {
            const float dx = sx - t0;
            const float dy = sy - t1;
            const float pws = __expf(p2) * aw * (1.0f / NET_W);
            const float phs = __expf(p3) * ah * (1.0f / NET_H);
            const float tws = __expf(t2) * aw * (1.0f / NET_W);
            const float ths = __expf(t3) * ah * (1.0f / NET_H);
            const float dw = pws - tws;
            const float dh = phs - ths;
            loss += (dx * dx + dy * dy + dw * dw + dh * dh) * COORD_SCALE;
            loss += diff2 * OBJ_SCALE;
            tc = (int)tgt[tbase + 5u * HW_];
        } else {
            // no_resp lane: om==1, cm==0 -> IOU gate on the noobj term
            const float col = (float)(hw % GW_);
            const float row = (float)(hw / GW_);

            const float pcx = (sx + col) * (NET_W / (float)GW_);
            const float pcy = (sy + row) * (NET_H / (float)GH_);
            const float pw  = __expf(p2) * aw;
            const float ph  = __expf(p3) * ah;
            const float px1 = pcx - 0.5f * pw;
            const float py1 = pcy - 0.5f * ph;
            const float px2 = px1 + pw;
            const float py2 = py1 + ph;

            const float gcx = (t0 + col) * (NET_W / (float)GW_);
            const float gcy = (t1 + row) * (NET_H / (float)GH_);
            const float gwd = __expf(t2) * aw;
            const float ghd = __expf(t3) * ah;
            const float gx1 = gcx - 0.5f * gwd;
            const float gy1 = gcy - 0.5f * ghd;
            const float gx2 = gx1 + gwd;
            const float gy2 = gy1 + ghd;

            const float iw = fmaxf(fminf(px2, gx2) - fmaxf(px1, gx1), 0.0f);
            const float ih = fmaxf(fminf(py2, gy2) - fmaxf(py1, gy1), 0.0f);
            const float inter  = iw * ih;
            const float area_p = (px2 - px1) * (py2 - py1);
            const float area_g = (gx2 - gx1) * (gy2 - gy1);
            const float iou = inter / (area_p + area_g - inter + 1e-9f);
            if (iou < OBJ_THRESH) {
                loss += diff2 * NOOBJ_SCALE;
            }
        }
    }

    // ---- wave-cooperative class CE (density ~0.2% of lanes) ----
    // For each lane with cm!=0, all 64 lanes load the 80 logits in parallel
    // (one ~900cy latency instead of an 80-iter serial strided loop).
    unsigned long long m = __ballot(want_ce);
    while (m) {
        const int src = __ffsll((long long)m) - 1;
        m &= m - 1;
        const unsigned nb  = (unsigned)__shfl((int)nbase, src, 64);
        const int      tcs = __shfl(tc, src, 64);

        const float x0 = net[nb + (unsigned)(5 + lane) * HW_];            // classes 0..63
        const float x1 = (lane < 16) ? net[nb + (unsigned)(69 + lane) * HW_]
                                     : -1e30f;                            // classes 64..79

        float mx = fmaxf(x0, x1);
        #pragma unroll
        for (int off = 32; off > 0; off >>= 1)
            mx = fmaxf(mx, __shfl_xor(mx, off, 64));

        float s = __expf(x0 - mx) + ((lane < 16) ? __expf(x1 - mx) : 0.0f);
        #pragma unroll
        for (int off = 32; off > 0; off >>= 1)
            s += __shfl_xor(s, off, 64);

        const int  idx = (tcs < 64) ? tcs : (tcs - 64);
        const float xa = __shfl(x0, idx, 64);
        const float xb = __shfl(x1, idx, 64);
        const float xt = (tcs < 64) ? xa : xb;

        const float ce = -(xt - mx - __logf(s));
        if (lane == src) loss += ce * CLASS_SCALE;
    }

    // ---- block reduction -> one plain store per block ----
    #pragma unroll
    for (int off = 32; off > 0; off >>= 1)
        loss += __shfl_down(loss, off, 64);

    __shared__ float wsum[4];
    const int wid = threadIdx.x >> 6;
    if (lane == 0) wsum[wid] = loss;
    __syncthreads();
    if (threadIdx.x == 0)
        partial[blockIdx.x] = wsum[0] + wsum[1] + wsum[2] + wsum[3];
}

__global__ __launch_bounds__(256) void yolo_reduce_kernel(
    const float* __restrict__ partial, float* __restrict__ out)
{
    float s = 0.0f;
    for (int j = threadIdx.x; j < GRID; j += BLOCK)
        s += partial[j];

    #pragma unroll
    for (int off = 32; off > 0; off >>= 1)
        s += __shfl_down(s, off, 64);

    __shared__ float w[4];
    const int lane = threadIdx.x & 63;
    const int wid  = threadIdx.x >> 6;
    if (lane == 0) w[wid] = s;
    __syncthreads();
    if (threadIdx.x == 0)
        out[0] = w[0] + w[1] + w[2] + w[3];
}

extern "C" void kernel_launch(void* const* d_in, const int* in_sizes, int n_in,
                              void* d_out, int out_size, void* d_ws, size_t ws_size,
                              hipStream_t stream) {
    const float* net     = (const float*)d_in[0];
    const float* tgt     = (const float*)d_in[1];
    const float* amask   = (const float*)d_in[2];
    const float* omask   = (const float*)d_in[3];
    const float* anchors = (const float*)d_in[4];
    float* out     = (float*)d_out;
    float* partial = (float*)d_ws;   // GRID floats, fully overwritten every launch

    yolo_partial_kernel<<<GRID, BLOCK, 0, stream>>>(net, tgt, amask, omask, anchors, partial);
    yolo_reduce_kernel<<<1, BLOCK, 0, stream>>>(partial, out);
}